// Round 1
// baseline (144.685 us; speedup 1.0000x reference)
//
#include <hip/hip_runtime.h>
#include <math.h>

#define BB 2
#define NN 512
#define DD 32
#define HH 64
#define JT (NN/256)             // j-tiles per row = 2
#define NPAIR (NN*NN)

// ws layout (float offsets)
#define SC_OFF   0                          // scores: B*N*N = 524288
#define UQ_OFF   (SC_OFF + BB*NN*NN)        // uq_T[b][l][n]: B*64*N = 65536
#define MT_OFF   (UQ_OFF + BB*HH*NN)        // M_T[l][k]: 4096
#define CV_OFF   (MT_OFF + HH*HH)           // cvec: 64
#define PM_OFF   (CV_OFF + HH)              // partial max: B*64
#define PS_OFF   (PM_OFF + BB*64)           // partial sumexp: B*64
#define ST_OFF   (PS_OFF + BB*64)           // per-batch {max, inv_sum}: B*2
#define A_OFF    (ST_OFF + BB*2)            // A accumulator: B*64
#define CS_OFF   (A_OFF + BB*HH)            // col sums: B*N

__device__ __forceinline__ void invar2(float pix, float piy, float piz,
                                       float pjx, float pjy, float pjz,
                                       float& s, float& cr) {
    // a = r_left = p_j, b = r_right = p_i (signs cancel under the norm)
    s = pix*pjx + piy*pjy + piz*pjz;
    float e12 = pjx*piy - pjy*pix;
    float e13 = pjx*piz - pjz*pix;
    float e23 = pjy*piz - pjz*piy;
    cr = sqrtf(e12*e12 + e13*e13 + e23*e23);
}

// ---------------- prep: uq_T, M_T, cvec, zero accumulators ----------------
__global__ __launch_bounds__(256) void prep(const float* __restrict__ values,
                                            const float* __restrict__ W2,
                                            const float* __restrict__ b2,
                                            const float* __restrict__ Ws1,
                                            const float* __restrict__ bs1,
                                            float* __restrict__ ws) {
    int idx = blockIdx.x * 256 + threadIdx.x;
    if (idx < BB*HH*NN) {
        // uq_T[b][l][n] = 0.25 * sum_d values[b][n][d] * Ws1[d][l]
        int n = idx % NN; int l = (idx / NN) % HH; int b = idx / (NN*HH);
        float acc = 0.f;
        #pragma unroll
        for (int d = 0; d < DD; d++) acc += values[(b*NN + n)*DD + d] * Ws1[d*HH + l];
        ws[UQ_OFF + idx] = 0.25f * acc;
    } else if (idx < BB*HH*NN + HH*HH) {
        int local = idx - BB*HH*NN;
        int k = local % HH, l = local / HH;
        float acc = 0.f;
        #pragma unroll
        for (int d = 0; d < DD; d++) acc += W2[k*DD + d] * Ws1[d*HH + l];
        ws[MT_OFF + l*HH + k] = acc;           // M_T[l][k] = (W2@Ws1)[k][l]
    } else if (idx < BB*HH*NN + HH*HH + HH) {
        int l = idx - BB*HH*NN - HH*HH;
        float acc = 0.f;
        #pragma unroll
        for (int d = 0; d < DD; d++) acc += b2[d] * Ws1[d*HH + l];
        ws[CV_OFF + l] = 0.5f * acc + bs1[l];
    } else if (idx < BB*HH*NN + HH*HH + HH + BB*HH + BB*NN) {
        int local = idx - (BB*HH*NN + HH*HH + HH);
        if (local < BB*HH) ws[A_OFF + local] = 0.f;
        else               ws[CS_OFF + (local - BB*HH)] = 0.f;
    }
}

// ---------------- pass1: per-pair score ----------------
__global__ __launch_bounds__(256) void pass1(const float* __restrict__ pos,
                                             const float* __restrict__ W1,
                                             const float* __restrict__ b1,
                                             const float* __restrict__ Ws2,
                                             const float* __restrict__ bs2,
                                             float* __restrict__ ws) {
    __shared__ float Mt[HH*HH];
    __shared__ float w1a[HH], w1b[HH], b1l[HH], cvl[HH], ws2l[HH], uqi[HH];
    int blk = blockIdx.x;
    int jt = blk % JT;
    int i  = (blk / JT) % NN;
    int b  = blk / (JT*NN);
    int tid = threadIdx.x;

    float4* Mt4 = (float4*)Mt;
    const float4* mtg4 = (const float4*)(ws + MT_OFF);
    #pragma unroll
    for (int q = 0; q < 4; q++) Mt4[tid + q*256] = mtg4[tid + q*256];
    if (tid < HH) {
        w1a[tid]  = W1[tid];
        w1b[tid]  = W1[HH + tid];
        b1l[tid]  = b1[tid];
        cvl[tid]  = ws[CV_OFF + tid];
        ws2l[tid] = Ws2[tid];
        uqi[tid]  = ws[UQ_OFF + (b*HH + tid)*NN + i];
    }
    __syncthreads();

    int j = jt*256 + tid;
    float pix = pos[(b*NN+i)*3+0], piy = pos[(b*NN+i)*3+1], piz = pos[(b*NN+i)*3+2];
    float pjx = pos[(b*NN+j)*3+0], pjy = pos[(b*NN+j)*3+1], pjz = pos[(b*NN+j)*3+2];
    float s, cr;
    invar2(pix,piy,piz,pjx,pjy,pjz,s,cr);

    float h[HH];
    #pragma unroll
    for (int k = 0; k < HH; k++) h[k] = fmaxf(w1a[k]*s + w1b[k]*cr + b1l[k], 0.f);

    const float* uq = ws + UQ_OFF + b*HH*NN;
    float score = bs2[0];
    #pragma unroll 4
    for (int l = 0; l < HH; l++) {
        const float4* row = (const float4*)(Mt + l*HH);
        float tl = 0.f;
        #pragma unroll
        for (int kk = 0; kk < 16; kk++) {
            float4 m4 = row[kk];
            tl += h[4*kk+0]*m4.x + h[4*kk+1]*m4.y + h[4*kk+2]*m4.z + h[4*kk+3]*m4.w;
        }
        float pre = 0.5f*tl + uqi[l] + uq[l*NN + j] + cvl[l];
        score += fmaxf(pre, 0.f) * ws2l[l];
    }
    ws[SC_OFF + (b*NN + i)*NN + j] = score;
}

// ---------------- pass2a: per-chunk online (max, sumexp) ----------------
__global__ __launch_bounds__(256) void pass2a(float* __restrict__ ws) {
    int blk = blockIdx.x;          // B*64 blocks, 4096 scores each
    int b = blk / 64;
    int chunk = blk % 64;
    const float4* sc4 = (const float4*)(ws + SC_OFF + b*NPAIR + chunk*4096);
    int tid = threadIdx.x;
    float x[16];
    #pragma unroll
    for (int q = 0; q < 4; q++) {
        float4 v = sc4[tid + q*256];
        x[4*q+0]=v.x; x[4*q+1]=v.y; x[4*q+2]=v.z; x[4*q+3]=v.w;
    }
    float m = x[0];
    #pragma unroll
    for (int q = 1; q < 16; q++) m = fmaxf(m, x[q]);
    float ssum = 0.f;
    #pragma unroll
    for (int q = 0; q < 16; q++) ssum += __expf(x[q] - m);
    for (int off = 1; off < 64; off <<= 1) {
        float om = __shfl_xor(m, off);
        float os = __shfl_xor(ssum, off);
        float nm = fmaxf(m, om);
        ssum = ssum*__expf(m - nm) + os*__expf(om - nm);
        m = nm;
    }
    __shared__ float sm[4], ssv[4];
    int w = tid >> 6;
    if ((tid & 63) == 0) { sm[w] = m; ssv[w] = ssum; }
    __syncthreads();
    if (tid == 0) {
        float M0 = sm[0], S0 = ssv[0];
        #pragma unroll
        for (int q = 1; q < 4; q++) {
            float nm = fmaxf(M0, sm[q]);
            S0 = S0*__expf(M0 - nm) + ssv[q]*__expf(sm[q] - nm);
            M0 = nm;
        }
        ws[PM_OFF + blk] = M0;
        ws[PS_OFF + blk] = S0;
    }
}

__global__ void pass2b(float* __restrict__ ws) {
    int b = threadIdx.x;
    if (b >= BB) return;
    float m = -INFINITY, ssum = 0.f;
    for (int p = 0; p < 64; p++) {
        float pm = ws[PM_OFF + b*64 + p], ps = ws[PS_OFF + b*64 + p];
        float nm = fmaxf(m, pm);
        ssum = ssum*__expf(m - nm) + ps*__expf(pm - nm);
        m = nm;
    }
    ws[ST_OFF + b*2]     = m;
    ws[ST_OFF + b*2 + 1] = 1.f / ssum;
}

// ---------------- pass3: accumulate A = sum att*h and col sums ----------------
__global__ __launch_bounds__(256) void pass3(const float* __restrict__ pos,
                                             const float* __restrict__ W1,
                                             const float* __restrict__ b1,
                                             float* __restrict__ ws) {
    __shared__ float w1a[HH], w1b[HH], b1l[HH];
    __shared__ float Aw[4*HH];
    int blk = blockIdx.x;          // B * (JT * 64 ichunks) = 256
    int b = blk / (JT*64);
    int lin = blk % (JT*64);
    int jt = lin % JT;
    int ic = lin / JT;             // 0..63, 8 i's each
    int tid = threadIdx.x;
    if (tid < HH) { w1a[tid] = W1[tid]; w1b[tid] = W1[HH+tid]; b1l[tid] = b1[tid]; }
    __syncthreads();

    int j = jt*256 + tid;
    float pjx = pos[(b*NN+j)*3+0], pjy = pos[(b*NN+j)*3+1], pjz = pos[(b*NN+j)*3+2];
    float maxv = ws[ST_OFF + b*2], inv = ws[ST_OFF + b*2 + 1];
    float A[HH];
    #pragma unroll
    for (int k = 0; k < HH; k++) A[k] = 0.f;
    float cs = 0.f;

    for (int ii = 0; ii < 8; ii++) {
        int i = ic*8 + ii;
        float pix = pos[(b*NN+i)*3+0], piy = pos[(b*NN+i)*3+1], piz = pos[(b*NN+i)*3+2];
        float s, cr;
        invar2(pix,piy,piz,pjx,pjy,pjz,s,cr);
        float w = __expf(ws[SC_OFF + (b*NN+i)*NN + j] - maxv) * inv;
        cs += w;
        #pragma unroll
        for (int k = 0; k < HH; k++) {
            float h = fmaxf(w1a[k]*s + w1b[k]*cr + b1l[k], 0.f);
            A[k] += w*h;
        }
    }
    atomicAdd(&ws[CS_OFF + b*NN + j], cs);

    #pragma unroll
    for (int k = 0; k < HH; k++) {
        for (int off = 1; off < 64; off <<= 1) A[k] += __shfl_xor(A[k], off);
    }
    int w = tid >> 6;
    if ((tid & 63) == 0) {
        #pragma unroll
        for (int k = 0; k < HH; k++) Aw[w*HH + k] = A[k];
    }
    __syncthreads();
    if (tid < HH) {
        float v = Aw[tid] + Aw[HH+tid] + Aw[2*HH+tid] + Aw[3*HH+tid];
        atomicAdd(&ws[A_OFF + b*HH + tid], v);
    }
}

// ---------------- final: out = 0.5*A@W2 + 0.5*b2 + 0.5*sum_n cs_n*v_n ----------------
__global__ void finalk(const float* __restrict__ values,
                       const float* __restrict__ W2,
                       const float* __restrict__ b2,
                       const float* __restrict__ ws,
                       float* __restrict__ out) {
    int tid = threadIdx.x;
    if (tid >= BB*DD) return;
    int b = tid / DD, d = tid % DD;
    float acc = 0.5f * b2[d];
    for (int k = 0; k < HH; k++) acc += 0.5f * ws[A_OFF + b*HH + k] * W2[k*DD + d];
    float acc2 = 0.f;
    for (int n = 0; n < NN; n++) acc2 += ws[CS_OFF + b*NN + n] * values[(b*NN + n)*DD + d];
    out[tid] = acc + 0.5f * acc2;
}

extern "C" void kernel_launch(void* const* d_in, const int* in_sizes, int n_in,
                              void* d_out, int out_size, void* d_ws, size_t ws_size,
                              hipStream_t stream) {
    (void)in_sizes; (void)n_in; (void)out_size; (void)ws_size;
    const float* pos    = (const float*)d_in[0];
    const float* values = (const float*)d_in[1];
    const float* W1     = (const float*)d_in[2];
    const float* b1     = (const float*)d_in[3];
    const float* W2     = (const float*)d_in[4];
    const float* b2     = (const float*)d_in[5];
    const float* Ws1    = (const float*)d_in[6];
    const float* bs1    = (const float*)d_in[7];
    const float* Ws2    = (const float*)d_in[8];
    const float* bs2    = (const float*)d_in[9];
    float* ws  = (float*)d_ws;
    float* out = (float*)d_out;

    int prep_threads = BB*HH*NN + HH*HH + HH + BB*HH + BB*NN;
    prep  <<<(prep_threads + 255)/256, 256, 0, stream>>>(values, W2, b2, Ws1, bs1, ws);
    pass1 <<<BB*NN*JT, 256, 0, stream>>>(pos, W1, b1, Ws2, bs2, ws);
    pass2a<<<BB*64, 256, 0, stream>>>(ws);
    pass2b<<<1, 64, 0, stream>>>(ws);
    pass3 <<<BB*JT*64, 256, 0, stream>>>(pos, W1, b1, ws);
    finalk<<<1, 64, 0, stream>>>(values, W2, b2, ws, out);
}

// Round 2
// 70.795 us; speedup vs baseline: 2.0437x; 2.0437x over previous
//
#include <hip/hip_runtime.h>
#include <math.h>

#define BB 2
#define NN 512
#define DD 32
#define HH 64
#define JT (NN/256)             // j-tiles per row = 2
#define NPAIR (NN*NN)

// ws layout (float offsets)
#define SC_OFF   0                          // scores: B*N*N = 524288
#define UQ_OFF   (SC_OFF + BB*NN*NN)        // uq_T[b][l][n]: B*64*N = 65536
#define MF_OFF   (UQ_OFF + BB*HH*NN)        // M B-fragments: 8 frags * 64 lanes * 8 f16 = 4096 halves = 2048 floats
#define CV_OFF   (MF_OFF + 2048)            // cvec: 64
#define PM_OFF   (CV_OFF + HH)              // partial max: B*64
#define PS_OFF   (PM_OFF + BB*64)           // partial sumexp: B*64
#define ST_OFF   (PS_OFF + BB*64)           // per-batch {max, inv_sum}: B*2
#define A_OFF    (ST_OFF + BB*2)            // A accumulator: B*64
#define CS_OFF   (A_OFF + BB*HH)            // col sums: B*N

typedef _Float16 half8 __attribute__((ext_vector_type(8)));
typedef _Float16 h2    __attribute__((ext_vector_type(2)));
typedef float    f32x4 __attribute__((ext_vector_type(4)));

union H8 { half8 v8; h2 p[4]; };

__device__ __forceinline__ void invar2(float pix, float piy, float piz,
                                       float pjx, float pjy, float pjz,
                                       float& s, float& cr) {
    s = pix*pjx + piy*pjy + piz*pjz;
    float e12 = pjx*piy - pjy*pix;
    float e13 = pjx*piz - pjz*pix;
    float e23 = pjy*piz - pjz*piy;
    cr = sqrtf(e12*e12 + e13*e13 + e23*e23);
}

// ---------------- prep: uq_T, M B-fragments, cvec, zero accumulators ----------------
// M B-fragment layout: frag f = cf*2+kh (cf=col-frag 0..3, kh=k-half 0..1)
//   lane l holds 8 f16: t=0..7 -> M[k][col], k = kh*32 + 8*(l>>4) + t, col = cf*16 + (l&15)
//   stored at halves index ((f*64)+l)*8 + t  (so each lane reads one contiguous 16B half8)
__global__ __launch_bounds__(256) void prep(const float* __restrict__ values,
                                            const float* __restrict__ W2,
                                            const float* __restrict__ b2,
                                            const float* __restrict__ Ws1,
                                            const float* __restrict__ bs1,
                                            float* __restrict__ ws) {
    int idx = blockIdx.x * 256 + threadIdx.x;
    if (idx < BB*HH*NN) {
        // uq_T[b][l][n] = 0.25 * sum_d values[b][n][d] * Ws1[d][l]
        int n = idx % NN; int l = (idx / NN) % HH; int b = idx / (NN*HH);
        float acc = 0.f;
        #pragma unroll
        for (int d = 0; d < DD; d++) acc += values[(b*NN + n)*DD + d] * Ws1[d*HH + l];
        ws[UQ_OFF + idx] = 0.25f * acc;
    } else if (idx < BB*HH*NN + 4096) {
        int e = idx - BB*HH*NN;          // 0..4095 half entries
        int t = e & 7;
        int lane = (e >> 3) & 63;
        int f = e >> 9;                  // 0..7
        int cf = f >> 1, kh = f & 1;
        int k   = kh*32 + 8*(lane >> 4) + t;
        int col = cf*16 + (lane & 15);
        float acc = 0.f;
        #pragma unroll
        for (int d = 0; d < DD; d++) acc += W2[k*DD + d] * Ws1[d*HH + col];
        ((_Float16*)(ws + MF_OFF))[e] = (_Float16)acc;
    } else if (idx < BB*HH*NN + 4096 + HH) {
        int l = idx - BB*HH*NN - 4096;
        float acc = 0.f;
        #pragma unroll
        for (int d = 0; d < DD; d++) acc += b2[d] * Ws1[d*HH + l];
        ws[CV_OFF + l] = 0.5f * acc + bs1[l];
    } else if (idx < BB*HH*NN + 4096 + HH + BB*HH + BB*NN) {
        int local = idx - (BB*HH*NN + 4096 + HH);
        if (local < BB*HH) ws[A_OFF + local] = 0.f;
        else               ws[CS_OFF + (local - BB*HH)] = 0.f;
    }
}

// ---------------- pass1: per-pair score via MFMA ----------------
// block = (b, i, jt).  4 waves, wave w owns j in [jt*256 + w*64, +64), all 64 l cols.
__global__ __launch_bounds__(256) void pass1(const float* __restrict__ pos,
                                             const float* __restrict__ W1,
                                             const float* __restrict__ b1,
                                             const float* __restrict__ Ws2,
                                             const float* __restrict__ bs2,
                                             float* __restrict__ ws) {
    __shared__ float uqc[HH];    // uq_i[l] + cvec[l]
    __shared__ float ws2l[HH];
    int blk = blockIdx.x;
    int jt = blk & (JT-1);
    int i  = (blk >> 1) & (NN-1);
    int b  = blk >> 10;
    int tid = threadIdx.x;
    int w    = tid >> 6;
    int lane = tid & 63;
    int g    = lane >> 4;
    int lr   = lane & 15;

    if (tid < HH) {
        uqc[tid]  = ws[UQ_OFF + (b*HH + tid)*NN + i] + ws[CV_OFF + tid];
        ws2l[tid] = Ws2[tid];
    }

    // B fragments (M), coalesced 16B per lane
    const half8* mf8 = (const half8*)(ws + MF_OFF);
    half8 Bf[4][2];
    #pragma unroll
    for (int cf = 0; cf < 4; cf++)
        #pragma unroll
        for (int kh = 0; kh < 2; kh++)
            Bf[cf][kh] = mf8[(cf*2 + kh)*64 + lane];

    // per-lane W1/b1 slices as packed f16 pairs: k = kh*32 + 8*g + 2*p + {0,1}
    h2 w1a2[2][4], w1b2[2][4], b12[2][4];
    #pragma unroll
    for (int kh = 0; kh < 2; kh++)
        #pragma unroll
        for (int p = 0; p < 4; p++) {
            int k0 = kh*32 + 8*g + 2*p;
            h2 a; a.x = (_Float16)W1[k0];      a.y = (_Float16)W1[k0+1];      w1a2[kh][p] = a;
            h2 c; c.x = (_Float16)W1[HH+k0];   c.y = (_Float16)W1[HH+k0+1];   w1b2[kh][p] = c;
            h2 d; d.x = (_Float16)b1[k0];      d.y = (_Float16)b1[k0+1];      b12[kh][p]  = d;
        }

    float pix = pos[(b*NN+i)*3+0], piy = pos[(b*NN+i)*3+1], piz = pos[(b*NN+i)*3+2];
    float bs2v = bs2[0];
    const float* uq_g = ws + UQ_OFF + b*HH*NN;
    float* sc_row = ws + SC_OFF + (size_t)(b*NN + i)*NN;

    __syncthreads();

    #pragma unroll
    for (int rf = 0; rf < 4; rf++) {
        // ---- A fragment: H rows j = base + (lane&15), k = kh*32 + 8*g + t ----
        int j_a = jt*256 + w*64 + rf*16 + lr;
        float pjx = pos[(b*NN+j_a)*3+0], pjy = pos[(b*NN+j_a)*3+1], pjz = pos[(b*NN+j_a)*3+2];
        float s, cr;
        invar2(pix,piy,piz,pjx,pjy,pjz,s,cr);
        h2 s2; s2.x = (_Float16)s; s2.y = s2.x;
        h2 c2; c2.x = (_Float16)cr; c2.y = c2.x;
        h2 z2; z2.x = (_Float16)0.f; z2.y = z2.x;
        H8 A0, A1;
        #pragma unroll
        for (int p = 0; p < 4; p++) {
            A0.p[p] = __builtin_elementwise_max(w1a2[0][p]*s2 + w1b2[0][p]*c2 + b12[0][p], z2);
            A1.p[p] = __builtin_elementwise_max(w1a2[1][p]*s2 + w1b2[1][p]*c2 + b12[1][p], z2);
        }

        // ---- GEMM: c[cf] = H @ M  (K=64 via two K=32 mfmas) ----
        f32x4 c[4];
        #pragma unroll
        for (int cf = 0; cf < 4; cf++) {
            f32x4 z = {0.f, 0.f, 0.f, 0.f};
            z = __builtin_amdgcn_mfma_f32_16x16x32_f16(A0.v8, Bf[cf][0], z, 0, 0, 0);
            c[cf] = __builtin_amdgcn_mfma_f32_16x16x32_f16(A1.v8, Bf[cf][1], z, 0, 0, 0);
        }

        // ---- epilogue: D row = 4*g + r, col = cf*16 + lr ----
        int jb4 = jt*256 + w*64 + rf*16 + 4*g;
        float part0 = 0.f, part1 = 0.f, part2 = 0.f, part3 = 0.f;
        #pragma unroll
        for (int cf = 0; cf < 4; cf++) {
            int lc = cf*16 + lr;
            float4 uq4 = *(const float4*)(uq_g + lc*NN + jb4);
            float base = uqc[lc];
            float w2v  = ws2l[lc];
            part0 += fmaxf(fmaf(0.5f, c[cf][0], base) + uq4.x, 0.f) * w2v;
            part1 += fmaxf(fmaf(0.5f, c[cf][1], base) + uq4.y, 0.f) * w2v;
            part2 += fmaxf(fmaf(0.5f, c[cf][2], base) + uq4.z, 0.f) * w2v;
            part3 += fmaxf(fmaf(0.5f, c[cf][3], base) + uq4.w, 0.f) * w2v;
        }
        // reduce across the 16 lanes of this group (cols)
        #pragma unroll
        for (int m = 1; m < 16; m <<= 1) {
            part0 += __shfl_xor(part0, m);
            part1 += __shfl_xor(part1, m);
            part2 += __shfl_xor(part2, m);
            part3 += __shfl_xor(part3, m);
        }
        if (lr == 0) {
            float4 outv;
            outv.x = part0 + bs2v; outv.y = part1 + bs2v;
            outv.z = part2 + bs2v; outv.w = part3 + bs2v;
            *(float4*)(sc_row + jb4) = outv;
        }
    }
}

// ---------------- pass2a: per-chunk online (max, sumexp) ----------------
__global__ __launch_bounds__(256) void pass2a(float* __restrict__ ws) {
    int blk = blockIdx.x;          // B*64 blocks, 4096 scores each
    int b = blk / 64;
    int chunk = blk % 64;
    const float4* sc4 = (const float4*)(ws + SC_OFF + b*NPAIR + chunk*4096);
    int tid = threadIdx.x;
    float x[16];
    #pragma unroll
    for (int q = 0; q < 4; q++) {
        float4 v = sc4[tid + q*256];
        x[4*q+0]=v.x; x[4*q+1]=v.y; x[4*q+2]=v.z; x[4*q+3]=v.w;
    }
    float m = x[0];
    #pragma unroll
    for (int q = 1; q < 16; q++) m = fmaxf(m, x[q]);
    float ssum = 0.f;
    #pragma unroll
    for (int q = 0; q < 16; q++) ssum += __expf(x[q] - m);
    for (int off = 1; off < 64; off <<= 1) {
        float om = __shfl_xor(m, off);
        float os = __shfl_xor(ssum, off);
        float nm = fmaxf(m, om);
        ssum = ssum*__expf(m - nm) + os*__expf(om - nm);
        m = nm;
    }
    __shared__ float sm[4], ssv[4];
    int w = tid >> 6;
    if ((tid & 63) == 0) { sm[w] = m; ssv[w] = ssum; }
    __syncthreads();
    if (tid == 0) {
        float M0 = sm[0], S0 = ssv[0];
        #pragma unroll
        for (int q = 1; q < 4; q++) {
            float nm = fmaxf(M0, sm[q]);
            S0 = S0*__expf(M0 - nm) + ssv[q]*__expf(sm[q] - nm);
            M0 = nm;
        }
        ws[PM_OFF + blk] = M0;
        ws[PS_OFF + blk] = S0;
    }
}

__global__ void pass2b(float* __restrict__ ws) {
    int b = threadIdx.x;
    if (b >= BB) return;
    float m = -INFINITY, ssum = 0.f;
    for (int p = 0; p < 64; p++) {
        float pm = ws[PM_OFF + b*64 + p], ps = ws[PS_OFF + b*64 + p];
        float nm = fmaxf(m, pm);
        ssum = ssum*__expf(m - nm) + ps*__expf(pm - nm);
        m = nm;
    }
    ws[ST_OFF + b*2]     = m;
    ws[ST_OFF + b*2 + 1] = 1.f / ssum;
}

// ---------------- pass3: accumulate A = sum att*h and col sums ----------------
__global__ __launch_bounds__(256) void pass3(const float* __restrict__ pos,
                                             const float* __restrict__ W1,
                                             const float* __restrict__ b1,
                                             float* __restrict__ ws) {
    __shared__ float w1a[HH], w1b[HH], b1l[HH];
    __shared__ float Aw[4*HH];
    int blk = blockIdx.x;          // B * (JT * 64 ichunks) = 256
    int b = blk / (JT*64);
    int lin = blk % (JT*64);
    int jt = lin % JT;
    int ic = lin / JT;             // 0..63, 8 i's each
    int tid = threadIdx.x;
    if (tid < HH) { w1a[tid] = W1[tid]; w1b[tid] = W1[HH+tid]; b1l[tid] = b1[tid]; }
    __syncthreads();

    int j = jt*256 + tid;
    float pjx = pos[(b*NN+j)*3+0], pjy = pos[(b*NN+j)*3+1], pjz = pos[(b*NN+j)*3+2];
    float maxv = ws[ST_OFF + b*2], inv = ws[ST_OFF + b*2 + 1];
    float A[HH];
    #pragma unroll
    for (int k = 0; k < HH; k++) A[k] = 0.f;
    float cs = 0.f;

    for (int ii = 0; ii < 8; ii++) {
        int i = ic*8 + ii;
        float pix = pos[(b*NN+i)*3+0], piy = pos[(b*NN+i)*3+1], piz = pos[(b*NN+i)*3+2];
        float s, cr;
        invar2(pix,piy,piz,pjx,pjy,pjz,s,cr);
        float w = __expf(ws[SC_OFF + (b*NN+i)*NN + j] - maxv) * inv;
        cs += w;
        #pragma unroll
        for (int k = 0; k < HH; k++) {
            float h = fmaxf(w1a[k]*s + w1b[k]*cr + b1l[k], 0.f);
            A[k] += w*h;
        }
    }
    atomicAdd(&ws[CS_OFF + b*NN + j], cs);

    #pragma unroll
    for (int k = 0; k < HH; k++) {
        for (int off = 1; off < 64; off <<= 1) A[k] += __shfl_xor(A[k], off);
    }
    int w = tid >> 6;
    if ((tid & 63) == 0) {
        #pragma unroll
        for (int k = 0; k < HH; k++) Aw[w*HH + k] = A[k];
    }
    __syncthreads();
    if (tid < HH) {
        float v = Aw[tid] + Aw[HH+tid] + Aw[2*HH+tid] + Aw[3*HH+tid];
        atomicAdd(&ws[A_OFF + b*HH + tid], v);
    }
}

// ---------------- final: out = 0.5*A@W2 + 0.5*b2 + 0.5*sum_n cs_n*v_n ----------------
__global__ void finalk(const float* __restrict__ values,
                       const float* __restrict__ W2,
                       const float* __restrict__ b2,
                       const float* __restrict__ ws,
                       float* __restrict__ out) {
    int tid = threadIdx.x;
    if (tid >= BB*DD) return;
    int b = tid / DD, d = tid % DD;
    float acc = 0.5f * b2[d];
    for (int k = 0; k < HH; k++) acc += 0.5f * ws[A_OFF + b*HH + k] * W2[k*DD + d];
    float acc2 = 0.f;
    for (int n = 0; n < NN; n++) acc2 += ws[CS_OFF + b*NN + n] * values[(b*NN + n)*DD + d];
    out[tid] = acc + 0.5f * acc2;
}

extern "C" void kernel_launch(void* const* d_in, const int* in_sizes, int n_in,
                              void* d_out, int out_size, void* d_ws, size_t ws_size,
                              hipStream_t stream) {
    (void)in_sizes; (void)n_in; (void)out_size; (void)ws_size;
    const float* pos    = (const float*)d_in[0];
    const float* values = (const float*)d_in[1];
    const float* W1     = (const float*)d_in[2];
    const float* b1     = (const float*)d_in[3];
    const float* W2     = (const float*)d_in[4];
    const float* b2     = (const float*)d_in[5];
    const float* Ws1    = (const float*)d_in[6];
    const float* bs1    = (const float*)d_in[7];
    const float* Ws2    = (const float*)d_in[8];
    const float* bs2    = (const float*)d_in[9];
    float* ws  = (float*)d_ws;
    float* out = (float*)d_out;

    int prep_threads = BB*HH*NN + 4096 + HH + BB*HH + BB*NN;
    prep  <<<(prep_threads + 255)/256, 256, 0, stream>>>(values, W2, b2, Ws1, bs1, ws);
    pass1 <<<BB*NN*JT, 256, 0, stream>>>(pos, W1, b1, Ws2, bs2, ws);
    pass2a<<<BB*64, 256, 0, stream>>>(ws);
    pass2b<<<1, 64, 0, stream>>>(ws);
    pass3 <<<BB*JT*64, 256, 0, stream>>>(pos, W1, b1, ws);
    finalk<<<1, 64, 0, stream>>>(values, W2, b2, ws, out);
}

// Round 3
// 65.574 us; speedup vs baseline: 2.2064x; 1.0796x over previous
//
#include <hip/hip_runtime.h>
#include <math.h>

#define BB 2
#define NN 512
#define DD 32
#define HH 64
#define JT (NN/256)             // j-tiles per row = 2
#define NPAIR (NN*NN)
#define NBLK1 (BB*NN*JT)        // pass1 blocks = 2048

// ws layout (float offsets)
#define SC_OFF   0                          // scores: B*N*N = 524288
#define UQ_OFF   (SC_OFF + BB*NN*NN)        // uq[b][n][l]: B*N*64 = 65536
#define MF_OFF   (UQ_OFF + BB*NN*HH)        // 0.5*M B-fragments: 8 frags*64 lanes*8 f16 = 4096 halves = 2048 fl
#define WF_OFF   (MF_OFF + 2048)            // 0.25*Ws1 B-fragments: 4 frags*64*8 = 2048 halves = 1024 fl
#define W1F_OFF  (WF_OFF + 1024)            // W1/b1 A-side table: 192 halves -> 128 fl (padded)
#define V16_OFF  (W1F_OFF + 128)            // values f16: B*N*32 = 32768 halves = 16384 fl
#define CV_OFF   (V16_OFF + 16384)          // cvec: 64
#define PM2_OFF  (CV_OFF + HH)              // per-pass1-block max: 2048
#define PS2_OFF  (PM2_OFF + NBLK1)          // per-pass1-block sumexp: 2048
#define ST_OFF   (PS2_OFF + NBLK1)          // per-batch {max, inv_sum}: B*2
#define A_OFF    (ST_OFF + BB*2)            // A accumulator: B*64
#define CS_OFF   (A_OFF + BB*HH)            // col sums: B*N

typedef _Float16 half8 __attribute__((ext_vector_type(8)));
typedef float    f32x4 __attribute__((ext_vector_type(4)));

__device__ __forceinline__ half8 h8splat(float v) {
    _Float16 h = (_Float16)v;
    half8 r = {h,h,h,h,h,h,h,h};
    return r;
}

__device__ __forceinline__ void invar2(float pix, float piy, float piz,
                                       float pjx, float pjy, float pjz,
                                       float& s, float& cr) {
    s = pix*pjx + piy*pjy + piz*pjz;
    float e12 = pjx*piy - pjy*pix;
    float e13 = pjx*piz - pjz*pix;
    float e23 = pjy*piz - pjz*piy;
    cr = sqrtf(e12*e12 + e13*e13 + e23*e23);
}

// prep ranges
#define R1 (BB*NN*HH)     // uq
#define R2 4096           // M fragments (halves)
#define R3 2048           // Ws1 fragments (halves)
#define R4 192            // W1/b1 table (halves)
#define R5 (BB*NN*DD)     // values -> f16
#define R6 HH             // cvec
#define R7 (BB*HH)        // zero A
#define R8 (BB*NN)        // zero CS
#define PREP_T (R1+R2+R3+R4+R5+R6+R7+R8)

__global__ __launch_bounds__(256) void prep(const float* __restrict__ values,
                                            const float* __restrict__ W1,
                                            const float* __restrict__ b1,
                                            const float* __restrict__ W2,
                                            const float* __restrict__ b2,
                                            const float* __restrict__ Ws1,
                                            const float* __restrict__ bs1,
                                            float* __restrict__ ws) {
    int idx = blockIdx.x * 256 + threadIdx.x;
    if (idx < R1) {
        // uq[b][n][l] = 0.25 * sum_d values[b][n][d] * Ws1[d][l]
        int l = idx % HH; int n = (idx / HH) % NN; int b = idx / (HH*NN);
        float acc = 0.f;
        #pragma unroll
        for (int d = 0; d < DD; d++) acc += values[(b*NN + n)*DD + d] * Ws1[d*HH + l];
        ws[UQ_OFF + idx] = 0.25f * acc;
    } else if (idx < R1+R2) {
        // 0.5*M fragment halves: e -> frag f=cf*2+kh, lane, t
        int e = idx - R1;
        int t = e & 7, lane = (e >> 3) & 63, f = e >> 9;
        int cf = f >> 1, kh = f & 1;
        int k   = kh*32 + 8*(lane >> 4) + t;
        int col = cf*16 + (lane & 15);
        float acc = 0.f;
        #pragma unroll
        for (int d = 0; d < DD; d++) acc += W2[k*DD + d] * Ws1[d*HH + col];
        ((_Float16*)(ws + MF_OFF))[e] = (_Float16)(0.5f * acc);
    } else if (idx < R1+R2+R3) {
        // 0.25*Ws1 fragment halves (K=32, k=d)
        int e = idx - R1 - R2;
        int t = e & 7, lane = (e >> 3) & 63, cf = e >> 9;
        int k   = 8*(lane >> 4) + t;
        int col = cf*16 + (lane & 15);
        ((_Float16*)(ws + WF_OFF))[e] = (_Float16)(0.25f * Ws1[k*HH + col]);
    } else if (idx < R1+R2+R3+R4) {
        // W1/b1 table: e = ((arr*2+kh)*4+g)*8+t, k = kh*32+8g+t
        int e = idx - R1 - R2 - R3;
        int t = e & 7, rest = e >> 3;
        int g = rest & 3, kh = (rest >> 2) & 1, arr = rest >> 3;
        int k = kh*32 + 8*g + t;
        float v = (arr == 0) ? W1[k] : (arr == 1) ? W1[HH + k] : b1[k];
        ((_Float16*)(ws + W1F_OFF))[e] = (_Float16)v;
    } else if (idx < R1+R2+R3+R4+R5) {
        int e = idx - R1 - R2 - R3 - R4;
        ((_Float16*)(ws + V16_OFF))[e] = (_Float16)values[e];
    } else if (idx < R1+R2+R3+R4+R5+R6) {
        int l = idx - R1 - R2 - R3 - R4 - R5;
        float acc = 0.f;
        #pragma unroll
        for (int d = 0; d < DD; d++) acc += b2[d] * Ws1[d*HH + l];
        ws[CV_OFF + l] = 0.5f * acc + bs1[l];
    } else if (idx < PREP_T) {
        int local = idx - (R1+R2+R3+R4+R5+R6);
        if (local < R7) ws[A_OFF + local] = 0.f;
        else            ws[CS_OFF + (local - R7)] = 0.f;
    }
}

// ---------------- pass1: scores via K=96 MFMA + fused softmax partials ----------------
// block = (b, i, jt). 4 waves, wave w owns j in [jt*256+w*64, +64).
__global__ __launch_bounds__(256) void pass1(const float* __restrict__ pos,
                                             const float* __restrict__ Ws2,
                                             const float* __restrict__ bs2,
                                             float* __restrict__ ws) {
    __shared__ float uqc[HH];    // uq_i[l] + cvec[l]
    __shared__ float ws2l[HH];
    __shared__ float sm4[4], ss4[4];
    int blk = blockIdx.x;
    int jt = blk & (JT-1);
    int i  = (blk >> 1) & (NN-1);
    int b  = blk >> 10;
    int tid = threadIdx.x;
    int w    = tid >> 6;
    int lane = tid & 63;
    int g    = lane >> 4;
    int lr   = lane & 15;

    if (tid < HH) {
        uqc[tid]  = ws[UQ_OFF + ((size_t)(b*NN + i))*HH + tid] + ws[CV_OFF + tid];
        ws2l[tid] = Ws2[tid];
    }

    // B fragments: 0.5*M (K=64 -> 2) and 0.25*Ws1 (K=32 -> 1), coalesced 16B/lane
    const half8* mf8 = (const half8*)(ws + MF_OFF);
    const half8* wf8 = (const half8*)(ws + WF_OFF);
    half8 Bf[4][2], Wf[4];
    #pragma unroll
    for (int cf = 0; cf < 4; cf++) {
        Bf[cf][0] = mf8[(cf*2 + 0)*64 + lane];
        Bf[cf][1] = mf8[(cf*2 + 1)*64 + lane];
        Wf[cf]    = wf8[cf*64 + lane];
    }
    // W1/b1 A-side slices (broadcast 16B loads)
    const half8* w1f8 = (const half8*)(ws + W1F_OFF);
    half8 W1a[2], W1b[2], B1f[2];
    #pragma unroll
    for (int kh = 0; kh < 2; kh++) {
        W1a[kh] = w1f8[(0*2 + kh)*4 + g];
        W1b[kh] = w1f8[(1*2 + kh)*4 + g];
        B1f[kh] = w1f8[(2*2 + kh)*4 + g];
    }

    float pix = pos[(b*NN+i)*3+0], piy = pos[(b*NN+i)*3+1], piz = pos[(b*NN+i)*3+2];
    float bs2v = bs2[0];
    const _Float16* v16 = (const _Float16*)(ws + V16_OFF);
    float* sc_row = ws + SC_OFF + (size_t)(b*NN + i)*NN;
    half8 z8 = h8splat(0.f);

    __syncthreads();

    float m_run = -INFINITY, s_run = 0.f;

    #pragma unroll
    for (int rf = 0; rf < 4; rf++) {
        // ---- A fragments: rows j = base + lr, k = kh*32 + 8g + t ----
        int j_a = jt*256 + w*64 + rf*16 + lr;
        float pjx = pos[(b*NN+j_a)*3+0], pjy = pos[(b*NN+j_a)*3+1], pjz = pos[(b*NN+j_a)*3+2];
        float s, cr;
        invar2(pix,piy,piz,pjx,pjy,pjz,s,cr);
        half8 s8 = h8splat(s), c8 = h8splat(cr);
        half8 A0 = __builtin_elementwise_max(W1a[0]*s8 + W1b[0]*c8 + B1f[0], z8);
        half8 A1 = __builtin_elementwise_max(W1a[1]*s8 + W1b[1]*c8 + B1f[1], z8);
        half8 A2 = *(const half8*)(v16 + ((size_t)(b*NN + j_a))*DD + 8*g);

        // ---- GEMM: c[cf] = [h | v_j] @ [0.5M ; 0.25Ws1]  (K=96) ----
        f32x4 c[4];
        #pragma unroll
        for (int cf = 0; cf < 4; cf++) {
            f32x4 z = {0.f, 0.f, 0.f, 0.f};
            z = __builtin_amdgcn_mfma_f32_16x16x32_f16(A0, Bf[cf][0], z, 0, 0, 0);
            z = __builtin_amdgcn_mfma_f32_16x16x32_f16(A1, Bf[cf][1], z, 0, 0, 0);
            c[cf] = __builtin_amdgcn_mfma_f32_16x16x32_f16(A2, Wf[cf], z, 0, 0, 0);
        }

        // ---- epilogue (register-only): D row = 4g+r, col = cf*16+lr ----
        float part0 = 0.f, part1 = 0.f, part2 = 0.f, part3 = 0.f;
        #pragma unroll
        for (int cf = 0; cf < 4; cf++) {
            int lc = cf*16 + lr;
            float base = uqc[lc];
            float w2v  = ws2l[lc];
            part0 += fmaxf(c[cf][0] + base, 0.f) * w2v;
            part1 += fmaxf(c[cf][1] + base, 0.f) * w2v;
            part2 += fmaxf(c[cf][2] + base, 0.f) * w2v;
            part3 += fmaxf(c[cf][3] + base, 0.f) * w2v;
        }
        #pragma unroll
        for (int m = 1; m < 16; m <<= 1) {
            part0 += __shfl_xor(part0, m);
            part1 += __shfl_xor(part1, m);
            part2 += __shfl_xor(part2, m);
            part3 += __shfl_xor(part3, m);
        }
        float x0 = part0 + bs2v, x1 = part1 + bs2v, x2 = part2 + bs2v, x3 = part3 + bs2v;
        if (lr == 0) {
            float4 outv; outv.x = x0; outv.y = x1; outv.z = x2; outv.w = x3;
            *(float4*)(sc_row + jt*256 + w*64 + rf*16 + 4*g) = outv;
        }
        // online stats (all lanes of a 16-group hold identical x values)
        float mm = fmaxf(fmaxf(x0, x1), fmaxf(x2, x3));
        float nm = fmaxf(m_run, mm);
        s_run = s_run*__expf(m_run - nm)
              + __expf(x0 - nm) + __expf(x1 - nm) + __expf(x2 - nm) + __expf(x3 - nm);
        m_run = nm;
    }

    // combine across the 4 g-groups (lr-duplicates are identical)
    #pragma unroll
    for (int off = 16; off < 64; off <<= 1) {
        float om = __shfl_xor(m_run, off);
        float os = __shfl_xor(s_run, off);
        float nm = fmaxf(m_run, om);
        s_run = s_run*__expf(m_run - nm) + os*__expf(om - nm);
        m_run = nm;
    }
    if (lane == 0) { sm4[w] = m_run; ss4[w] = s_run; }
    __syncthreads();
    if (tid == 0) {
        float M0 = sm4[0], S0 = ss4[0];
        #pragma unroll
        for (int q = 1; q < 4; q++) {
            float nm = fmaxf(M0, sm4[q]);
            S0 = S0*__expf(M0 - nm) + ss4[q]*__expf(sm4[q] - nm);
            M0 = nm;
        }
        ws[PM2_OFF + blk] = M0;
        ws[PS2_OFF + blk] = S0;
    }
}

// ---------------- pass2b: reduce 1024 partials per batch ----------------
__global__ __launch_bounds__(256) void pass2b(float* __restrict__ ws) {
    int b = blockIdx.x;
    int tid = threadIdx.x;
    int base = b * (NN*JT);
    float m = -INFINITY, ssum = 0.f;
    #pragma unroll
    for (int q = 0; q < 4; q++) {
        int p = base + tid + q*256;
        float pm = ws[PM2_OFF + p], ps = ws[PS2_OFF + p];
        float nm = fmaxf(m, pm);
        ssum = ssum*__expf(m - nm) + ps*__expf(pm - nm);
        m = nm;
    }
    for (int off = 1; off < 64; off <<= 1) {
        float om = __shfl_xor(m, off);
        float os = __shfl_xor(ssum, off);
        float nm = fmaxf(m, om);
        ssum = ssum*__expf(m - nm) + os*__expf(om - nm);
        m = nm;
    }
    __shared__ float sm[4], ssv[4];
    int w = tid >> 6;
    if ((tid & 63) == 0) { sm[w] = m; ssv[w] = ssum; }
    __syncthreads();
    if (tid == 0) {
        float M0 = sm[0], S0 = ssv[0];
        #pragma unroll
        for (int q = 1; q < 4; q++) {
            float nm = fmaxf(M0, sm[q]);
            S0 = S0*__expf(M0 - nm) + ssv[q]*__expf(sm[q] - nm);
            M0 = nm;
        }
        ws[ST_OFF + b*2]     = M0;
        ws[ST_OFF + b*2 + 1] = 1.f / S0;
    }
}

// ---------------- pass3: accumulate A = sum att*h and col sums ----------------
__global__ __launch_bounds__(256) void pass3(const float* __restrict__ pos,
                                             const float* __restrict__ W1,
                                             const float* __restrict__ b1,
                                             float* __restrict__ ws) {
    __shared__ float w1a[HH], w1b[HH], b1l[HH];
    __shared__ float Aw[4*HH];
    int blk = blockIdx.x;          // B * (JT * 64 ichunks) = 256
    int b = blk / (JT*64);
    int lin = blk % (JT*64);
    int jt = lin % JT;
    int ic = lin / JT;             // 0..63, 8 i's each
    int tid = threadIdx.x;
    if (tid < HH) { w1a[tid] = W1[tid]; w1b[tid] = W1[HH+tid]; b1l[tid] = b1[tid]; }
    __syncthreads();

    int j = jt*256 + tid;
    float pjx = pos[(b*NN+j)*3+0], pjy = pos[(b*NN+j)*3+1], pjz = pos[(b*NN+j)*3+2];
    float maxv = ws[ST_OFF + b*2], inv = ws[ST_OFF + b*2 + 1];
    float A[HH];
    #pragma unroll
    for (int k = 0; k < HH; k++) A[k] = 0.f;
    float cs = 0.f;

    for (int ii = 0; ii < 8; ii++) {
        int i = ic*8 + ii;
        float pix = pos[(b*NN+i)*3+0], piy = pos[(b*NN+i)*3+1], piz = pos[(b*NN+i)*3+2];
        float s, cr;
        invar2(pix,piy,piz,pjx,pjy,pjz,s,cr);
        float w = __expf(ws[SC_OFF + (size_t)(b*NN+i)*NN + j] - maxv) * inv;
        cs += w;
        #pragma unroll
        for (int k = 0; k < HH; k++) {
            float h = fmaxf(w1a[k]*s + w1b[k]*cr + b1l[k], 0.f);
            A[k] += w*h;
        }
    }
    atomicAdd(&ws[CS_OFF + b*NN + j], cs);

    #pragma unroll
    for (int k = 0; k < HH; k++) {
        for (int off = 1; off < 64; off <<= 1) A[k] += __shfl_xor(A[k], off);
    }
    int w = tid >> 6;
    if ((tid & 63) == 0) {
        #pragma unroll
        for (int k = 0; k < HH; k++) Aw[w*HH + k] = A[k];
    }
    __syncthreads();
    if (tid < HH) {
        float v = Aw[tid] + Aw[HH+tid] + Aw[2*HH+tid] + Aw[3*HH+tid];
        atomicAdd(&ws[A_OFF + b*HH + tid], v);
    }
}

// ---------------- final ----------------
__global__ void finalk(const float* __restrict__ values,
                       const float* __restrict__ W2,
                       const float* __restrict__ b2,
                       const float* __restrict__ ws,
                       float* __restrict__ out) {
    int tid = threadIdx.x;
    if (tid >= BB*DD) return;
    int b = tid / DD, d = tid % DD;
    float acc = 0.5f * b2[d];
    for (int k = 0; k < HH; k++) acc += 0.5f * ws[A_OFF + b*HH + k] * W2[k*DD + d];
    float acc2 = 0.f;
    for (int n = 0; n < NN; n++) acc2 += ws[CS_OFF + b*NN + n] * values[(b*NN + n)*DD + d];
    out[tid] = acc + 0.5f * acc2;
}

extern "C" void kernel_launch(void* const* d_in, const int* in_sizes, int n_in,
                              void* d_out, int out_size, void* d_ws, size_t ws_size,
                              hipStream_t stream) {
    (void)in_sizes; (void)n_in; (void)out_size; (void)ws_size;
    const float* pos    = (const float*)d_in[0];
    const float* values = (const float*)d_in[1];
    const float* W1     = (const float*)d_in[2];
    const float* b1     = (const float*)d_in[3];
    const float* W2     = (const float*)d_in[4];
    const float* b2     = (const float*)d_in[5];
    const float* Ws1    = (const float*)d_in[6];
    const float* bs1    = (const float*)d_in[7];
    const float* Ws2    = (const float*)d_in[8];
    const float* bs2    = (const float*)d_in[9];
    float* ws  = (float*)d_ws;
    float* out = (float*)d_out;

    prep  <<<(PREP_T + 255)/256, 256, 0, stream>>>(values, W1, b1, W2, b2, Ws1, bs1, ws);
    pass1 <<<NBLK1, 256, 0, stream>>>(pos, Ws2, bs2, ws);
    pass2b<<<BB, 256, 0, stream>>>(ws);
    pass3 <<<BB*JT*64, 256, 0, stream>>>(pos, W1, b1, ws);
    finalk<<<1, 64, 0, stream>>>(values, W2, b2, ws, out);
}